// Round 3
// baseline (4442.293 us; speedup 1.0000x reference)
//
#include <hip/hip_runtime.h>

#define FD 128  // feature dim (H = O = 128)

__device__ __forceinline__ float lrelu(float x) { return x > 0.f ? x : 0.2f * x; }

__device__ __forceinline__ void fma4(float4& acc, float s, const float4& w) {
    acc.x = fmaf(s, w.x, acc.x);
    acc.y = fmaf(s, w.y, acc.y);
    acc.z = fmaf(s, w.z, acc.z);
    acc.w = fmaf(s, w.w, acc.w);
}

// ---------- degree / norm ----------
__global__ void k_init_deg(float* deg, int n) {
    int i = blockIdx.x * blockDim.x + threadIdx.x;
    if (i < n) deg[i] = 1.0f;  // self-loop
}

__global__ void k_count(const int* __restrict__ dst, float* deg, int e) {
    int i = blockIdx.x * blockDim.x + threadIdx.x;
    if (i < e) atomicAdd(&deg[dst[i]], 1.0f);
}

__global__ void k_dinv(const float* __restrict__ deg, float* dinv, int n) {
    int i = blockIdx.x * blockDim.x + threadIdx.x;
    if (i < n) dinv[i] = rsqrtf(deg[i]);  // deg >= 1 always
}

// ---------- GEMM: C[n,128] = act(A[n,128] @ W[128,128] (+ b)) ----------
// block = 256 threads -> 32 rows x 128 cols; thread computes 4 rows x 4 cols.
// In-place safe (A == C): all reads happen before __syncthreads, stores after,
// and rows are block-exclusive.
template <bool BIAS_RELU>
__global__ __launch_bounds__(256) void k_gemm128(const float* A, const float* __restrict__ W,
                                                 const float* __restrict__ b, float* C, int n) {
    const int tx = threadIdx.x & 31;   // col group: cols tx*4 .. tx*4+3
    const int ty = threadIdx.x >> 5;   // row group 0..7
    const int c0 = tx * 4;
    const int row0 = blockIdx.x * 32 + ty * 4;

    // clamp reads for the partial last block (clamped rows stay block-local)
    const int r0 = min(row0 + 0, n - 1);
    const int r1 = min(row0 + 1, n - 1);
    const int r2 = min(row0 + 2, n - 1);
    const int r3 = min(row0 + 3, n - 1);
    const float* A0 = A + (size_t)r0 * FD;
    const float* A1 = A + (size_t)r1 * FD;
    const float* A2 = A + (size_t)r2 * FD;
    const float* A3 = A + (size_t)r3 * FD;

    float4 acc0 = {0.f, 0.f, 0.f, 0.f}, acc1 = acc0, acc2 = acc0, acc3 = acc0;

    #pragma unroll 8
    for (int k = 0; k < FD; k += 4) {
        float4 w0 = *(const float4*)(W + (size_t)(k + 0) * FD + c0);
        float4 w1 = *(const float4*)(W + (size_t)(k + 1) * FD + c0);
        float4 w2 = *(const float4*)(W + (size_t)(k + 2) * FD + c0);
        float4 w3 = *(const float4*)(W + (size_t)(k + 3) * FD + c0);
        float4 a0 = *(const float4*)(A0 + k);
        float4 a1 = *(const float4*)(A1 + k);
        float4 a2 = *(const float4*)(A2 + k);
        float4 a3 = *(const float4*)(A3 + k);
        fma4(acc0, a0.x, w0); fma4(acc0, a0.y, w1); fma4(acc0, a0.z, w2); fma4(acc0, a0.w, w3);
        fma4(acc1, a1.x, w0); fma4(acc1, a1.y, w1); fma4(acc1, a1.z, w2); fma4(acc1, a1.w, w3);
        fma4(acc2, a2.x, w0); fma4(acc2, a2.y, w1); fma4(acc2, a2.z, w2); fma4(acc2, a2.w, w3);
        fma4(acc3, a3.x, w0); fma4(acc3, a3.y, w1); fma4(acc3, a3.z, w2); fma4(acc3, a3.w, w3);
    }

    __syncthreads();  // all in-place reads complete before any store

    float4 bias = {0.f, 0.f, 0.f, 0.f};
    if (BIAS_RELU) bias = *(const float4*)(b + c0);

    float4 accs[4] = {acc0, acc1, acc2, acc3};
    #pragma unroll
    for (int r = 0; r < 4; ++r) {
        int row = row0 + r;
        if (row < n) {
            float4 v = accs[r];
            if (BIAS_RELU) {
                v.x = fmaxf(v.x + bias.x, 0.f);
                v.y = fmaxf(v.y + bias.y, 0.f);
                v.z = fmaxf(v.z + bias.z, 0.f);
                v.w = fmaxf(v.w + bias.w, 0.f);
            }
            *(float4*)(C + (size_t)row * FD + c0) = v;
        }
    }
}

// ---------- GCN aggregation ----------
// self-loop term initializes agg: agg[i] = dinv[i]^2 * m[i]
__global__ void k_gcn_self(const float* __restrict__ m, const float* __restrict__ dinv,
                           float* __restrict__ agg, int n) {
    int t = blockIdx.x * blockDim.x + threadIdx.x;
    int i = t >> 5, lane = t & 31;
    if (i >= n) return;
    float c = dinv[i]; c = c * c;
    float4 v = *(const float4*)(m + (size_t)i * FD + lane * 4);
    *(float4*)(agg + (size_t)i * FD + lane * 4) = make_float4(c * v.x, c * v.y, c * v.z, c * v.w);
}

// per edge: agg[d] += dinv[s]*dinv[d] * m[s]   (32 lanes/edge, float4 each)
__global__ void k_gcn_scatter(const float* __restrict__ m, const int* __restrict__ src,
                              const int* __restrict__ dst, const float* __restrict__ dinv,
                              float* agg, int e) {
    int t = blockIdx.x * blockDim.x + threadIdx.x;
    int ei = t >> 5, lane = t & 31;
    if (ei >= e) return;
    int s = src[ei], d = dst[ei];
    float c = dinv[s] * dinv[d];
    float4 v = *(const float4*)(m + (size_t)s * FD + lane * 4);
    float* o = agg + (size_t)d * FD + lane * 4;
    atomicAdd(o + 0, c * v.x);
    atomicAdd(o + 1, c * v.y);
    atomicAdd(o + 2, c * v.z);
    atomicAdd(o + 3, c * v.w);
}

__global__ void k_bias_relu(float* h, const float* __restrict__ b, int n) {
    int t = blockIdx.x * blockDim.x + threadIdx.x;
    int i = t >> 5, lane = t & 31;
    if (i >= n) return;
    float4* p = (float4*)(h + (size_t)i * FD + lane * 4);
    float4 v = *p;
    float4 bb = *(const float4*)(b + lane * 4);
    v.x = fmaxf(v.x + bb.x, 0.f);
    v.y = fmaxf(v.y + bb.y, 0.f);
    v.z = fmaxf(v.z + bb.z, 0.f);
    v.w = fmaxf(v.w + bb.w, 0.f);
    *p = v;
}

// ---------- GAT ----------
// per-node attention scalars: asrc[i] = g[i].a_src, adst[i] = g[i].a_dst
__global__ void k_av(const float* __restrict__ g, const float* __restrict__ a_src,
                     const float* __restrict__ a_dst, float* asrc, float* adst, int n) {
    int t = blockIdx.x * blockDim.x + threadIdx.x;
    int i = t >> 6, lane = t & 63;
    if (i >= n) return;
    float2 gv = *(const float2*)(g + (size_t)i * FD + lane * 2);
    float2 as = *(const float2*)(a_src + lane * 2);
    float2 ad = *(const float2*)(a_dst + lane * 2);
    float ps = gv.x * as.x + gv.y * as.y;
    float pd = gv.x * ad.x + gv.y * ad.y;
    #pragma unroll
    for (int m = 32; m; m >>= 1) {
        ps += __shfl_xor(ps, m);
        pd += __shfl_xor(pd, m);
    }
    if (lane == 0) { asrc[i] = ps; adst[i] = pd; }
}

// self-loop: denom[i] = exp(lrelu(asrc[i]+adst[i])); acc[i] = denom[i]*g[i]
// (no max-subtraction: logits are O(+-10), exp() is safe and math-identical)
__global__ void k_gat_self(const float* __restrict__ g, const float* __restrict__ asrc,
                           const float* __restrict__ adst, float* denom, float* acc, int n) {
    int t = blockIdx.x * blockDim.x + threadIdx.x;
    int i = t >> 5, lane = t & 31;
    if (i >= n) return;
    float es = expf(lrelu(asrc[i] + adst[i]));
    if (lane == 0) denom[i] = es;
    float4 v = *(const float4*)(g + (size_t)i * FD + lane * 4);
    *(float4*)(acc + (size_t)i * FD + lane * 4) = make_float4(es * v.x, es * v.y, es * v.z, es * v.w);
}

__global__ void k_gat_denom(const int* __restrict__ src, const int* __restrict__ dst,
                            const float* __restrict__ asrc, const float* __restrict__ adst,
                            float* denom, int e) {
    int i = blockIdx.x * blockDim.x + threadIdx.x;
    if (i >= e) return;
    atomicAdd(&denom[dst[i]], expf(lrelu(asrc[src[i]] + adst[dst[i]])));
}

__global__ void k_gat_scatter(const float* __restrict__ g, const int* __restrict__ src,
                              const int* __restrict__ dst, const float* __restrict__ asrc,
                              const float* __restrict__ adst, float* acc, int e) {
    int t = blockIdx.x * blockDim.x + threadIdx.x;
    int ei = t >> 5, lane = t & 31;
    if (ei >= e) return;
    int s = src[ei], d = dst[ei];
    float w = expf(lrelu(asrc[s] + adst[d]));
    float4 v = *(const float4*)(g + (size_t)s * FD + lane * 4);
    float* o = acc + (size_t)d * FD + lane * 4;
    atomicAdd(o + 0, w * v.x);
    atomicAdd(o + 1, w * v.y);
    atomicAdd(o + 2, w * v.z);
    atomicAdd(o + 3, w * v.w);
}

// ---------- final mean over nodes ----------
__global__ void k_zero_out(float* out) { out[threadIdx.x] = 0.f; }

__global__ void k_reduce(const float* __restrict__ acc, const float* __restrict__ denom,
                         float* out, int n) {
    const int sub = threadIdx.x >> 7;  // 0..1
    const int c = threadIdx.x & 127;
    float r = 0.f;
    for (int i = blockIdx.x * 2 + sub; i < n; i += gridDim.x * 2)
        r += acc[(size_t)i * FD + c] / denom[i];
    __shared__ float lds[256];
    lds[threadIdx.x] = r;
    __syncthreads();
    if (threadIdx.x < 128) atomicAdd(&out[c], lds[threadIdx.x] + lds[threadIdx.x + 128]);
}

__global__ void k_final(float* out, const float* __restrict__ bg, float invn) {
    int c = threadIdx.x;
    out[c] = out[c] * invn + bg[c];
}

// ---------- launch ----------
extern "C" void kernel_launch(void* const* d_in, const int* in_sizes, int n_in,
                              void* d_out, int out_size, void* d_ws, size_t ws_size,
                              hipStream_t stream) {
    const float* x      = (const float*)d_in[0];
    const int*   ei     = (const int*)d_in[1];
    const float* W_emb  = (const float*)d_in[2];
    const float* b_emb  = (const float*)d_in[3];
    const float* W1     = (const float*)d_in[4];
    const float* b1     = (const float*)d_in[5];
    const float* W2     = (const float*)d_in[6];
    const float* b2     = (const float*)d_in[7];
    const float* Wg     = (const float*)d_in[8];
    const float* a_src  = (const float*)d_in[9];
    const float* a_dst  = (const float*)d_in[10];
    const float* bg     = (const float*)d_in[11];

    const int n = in_sizes[0] / FD;   // 50000
    const int e = in_sizes[1] / 2;    // 800000
    const int* src = ei;
    const int* dst = ei + e;

    float* bufA  = (float*)d_ws;
    float* bufB  = bufA + (size_t)n * FD;
    float* deg   = bufB + (size_t)n * FD;
    float* dinv  = deg + n;
    float* asrc  = dinv + n;
    float* adst  = asrc + n;
    float* denom = adst + n;

    const dim3 B(256);
    const int gn    = (n + 255) / 256;
    const int ge    = (e + 255) / 256;
    const int gn32  = (n * 32 + 255) / 256;
    const int ge32  = (int)(((long long)e * 32 + 255) / 256);
    const int grows = (n + 31) / 32;

    // degrees & symmetric norm
    k_init_deg<<<gn, B, 0, stream>>>(deg, n);
    k_count<<<ge, B, 0, stream>>>(dst, deg, e);
    k_dinv<<<gn, B, 0, stream>>>(deg, dinv, n);

    // h0 = relu(x @ W_emb + b_emb) -> bufA
    k_gemm128<true><<<grows, B, 0, stream>>>(x, W_emb, b_emb, bufA, n);

    // GCN layer 1: m = h0@W1 (in-place bufA); agg -> bufB; h1 = relu(agg+b1)
    k_gemm128<false><<<grows, B, 0, stream>>>(bufA, W1, nullptr, bufA, n);
    k_gcn_self<<<gn32, B, 0, stream>>>(bufA, dinv, bufB, n);
    k_gcn_scatter<<<ge32, B, 0, stream>>>(bufA, src, dst, dinv, bufB, e);
    k_bias_relu<<<gn32, B, 0, stream>>>(bufB, b1, n);

    // GCN layer 2: m = h1@W2 (in-place bufB); agg -> bufA; h2 = relu(agg+b2)
    k_gemm128<false><<<grows, B, 0, stream>>>(bufB, W2, nullptr, bufB, n);
    k_gcn_self<<<gn32, B, 0, stream>>>(bufB, dinv, bufA, n);
    k_gcn_scatter<<<ge32, B, 0, stream>>>(bufB, src, dst, dinv, bufA, e);
    k_bias_relu<<<gn32, B, 0, stream>>>(bufA, b2, n);

    // GAT: g = h2 @ Wg (in-place bufA)
    k_gemm128<false><<<grows, B, 0, stream>>>(bufA, Wg, nullptr, bufA, n);
    k_av<<<(n * 64 + 255) / 256, B, 0, stream>>>(bufA, a_src, a_dst, asrc, adst, n);
    k_gat_self<<<gn32, B, 0, stream>>>(bufA, asrc, adst, denom, bufB, n);
    k_gat_denom<<<ge, B, 0, stream>>>(src, dst, asrc, adst, denom, e);
    k_gat_scatter<<<ge32, B, 0, stream>>>(bufA, src, dst, asrc, adst, bufB, e);

    // out[c] = mean_i(acc[i][c]/denom[i]) + bg[c]
    k_zero_out<<<1, FD, 0, stream>>>((float*)d_out);
    k_reduce<<<256, B, 0, stream>>>(bufB, denom, (float*)d_out, n);
    k_final<<<1, FD, 0, stream>>>((float*)d_out, bg, 1.0f / n);
}

// Round 4
// 556.546 us; speedup vs baseline: 7.9819x; 7.9819x over previous
//
#include <hip/hip_runtime.h>

#define FD 128  // feature dim (H = O = 128)

__device__ __forceinline__ float lrelu(float x) { return x > 0.f ? x : 0.2f * x; }

__device__ __forceinline__ void fma4(float4& acc, float s, const float4& w) {
    acc.x = fmaf(s, w.x, acc.x);
    acc.y = fmaf(s, w.y, acc.y);
    acc.z = fmaf(s, w.z, acc.z);
    acc.w = fmaf(s, w.w, acc.w);
}

// ---------- CSR build ----------
__global__ void k_zero_int(int* p, int n) {
    int i = blockIdx.x * blockDim.x + threadIdx.x;
    if (i < n) p[i] = 0;
}

__global__ void k_hist(const int* __restrict__ dst, int* cnt, int e) {
    int i = blockIdx.x * blockDim.x + threadIdx.x;
    if (i < e) atomicAdd(&cnt[dst[i]], 1);
}

// inclusive block scan -> rowptr (per-block inclusive), bsum = block totals
__global__ __launch_bounds__(256) void k_scan1(const int* __restrict__ cnt, int* rowptr,
                                               int* bsum, int n) {
    __shared__ int lds[256];
    int i = blockIdx.x * 256 + threadIdx.x;
    int v = (i < n) ? cnt[i] : 0;
    lds[threadIdx.x] = v;
    __syncthreads();
    for (int off = 1; off < 256; off <<= 1) {
        int t = (threadIdx.x >= off) ? lds[threadIdx.x - off] : 0;
        __syncthreads();
        lds[threadIdx.x] += t;
        __syncthreads();
    }
    if (i < n) rowptr[i] = lds[threadIdx.x];
    if (threadIdx.x == 255) bsum[blockIdx.x] = lds[255];
}

// single-block inclusive scan of block sums (nb <= 256)
__global__ __launch_bounds__(256) void k_scan2(int* bsum, int nb) {
    __shared__ int lds[256];
    int v = (threadIdx.x < nb) ? bsum[threadIdx.x] : 0;
    lds[threadIdx.x] = v;
    __syncthreads();
    for (int off = 1; off < 256; off <<= 1) {
        int t = (threadIdx.x >= off) ? lds[threadIdx.x - off] : 0;
        __syncthreads();
        lds[threadIdx.x] += t;
        __syncthreads();
    }
    if (threadIdx.x < nb) bsum[threadIdx.x] = lds[threadIdx.x];
}

// rowptr[i] = exclusive prefix = (inclusive within block) - cnt[i] + prev-block offset
__global__ void k_scan3(int* rowptr, const int* __restrict__ cnt,
                        const int* __restrict__ bsum, int n) {
    int i = blockIdx.x * 256 + threadIdx.x;
    if (i >= n) return;
    int off = (blockIdx.x > 0) ? bsum[blockIdx.x - 1] : 0;
    rowptr[i] = rowptr[i] - cnt[i] + off;
}

__global__ void k_fill(const int* __restrict__ src, const int* __restrict__ dst,
                       const int* __restrict__ rowptr, int* cursor, int* col, int e) {
    int i = blockIdx.x * blockDim.x + threadIdx.x;
    if (i >= e) return;
    int d = dst[i];
    int pos = atomicAdd(&cursor[d], 1);
    col[rowptr[d] + pos] = src[i];
}

__global__ void k_dinv(const int* __restrict__ cnt, float* dinv, int n) {
    int i = blockIdx.x * blockDim.x + threadIdx.x;
    if (i < n) dinv[i] = rsqrtf((float)cnt[i] + 1.0f);  // +1 self-loop
}

// ---------- GEMM: C[n,128] = act(A[n,128] @ W[128,128] (+ b)) ----------
// block = 256 threads -> 32 rows x 128 cols; thread computes 4 rows x 4 cols.
// In-place safe (A == C): reads before __syncthreads, stores after; rows block-exclusive.
template <bool BIAS_RELU>
__global__ __launch_bounds__(256) void k_gemm128(const float* A, const float* __restrict__ W,
                                                 const float* __restrict__ b, float* C, int n) {
    const int tx = threadIdx.x & 31;
    const int ty = threadIdx.x >> 5;
    const int c0 = tx * 4;
    const int row0 = blockIdx.x * 32 + ty * 4;

    const int r0 = min(row0 + 0, n - 1);
    const int r1 = min(row0 + 1, n - 1);
    const int r2 = min(row0 + 2, n - 1);
    const int r3 = min(row0 + 3, n - 1);
    const float* A0 = A + (size_t)r0 * FD;
    const float* A1 = A + (size_t)r1 * FD;
    const float* A2 = A + (size_t)r2 * FD;
    const float* A3 = A + (size_t)r3 * FD;

    float4 acc0 = {0.f, 0.f, 0.f, 0.f}, acc1 = acc0, acc2 = acc0, acc3 = acc0;

    #pragma unroll 8
    for (int k = 0; k < FD; k += 4) {
        float4 w0 = *(const float4*)(W + (size_t)(k + 0) * FD + c0);
        float4 w1 = *(const float4*)(W + (size_t)(k + 1) * FD + c0);
        float4 w2 = *(const float4*)(W + (size_t)(k + 2) * FD + c0);
        float4 w3 = *(const float4*)(W + (size_t)(k + 3) * FD + c0);
        float4 a0 = *(const float4*)(A0 + k);
        float4 a1 = *(const float4*)(A1 + k);
        float4 a2 = *(const float4*)(A2 + k);
        float4 a3 = *(const float4*)(A3 + k);
        fma4(acc0, a0.x, w0); fma4(acc0, a0.y, w1); fma4(acc0, a0.z, w2); fma4(acc0, a0.w, w3);
        fma4(acc1, a1.x, w0); fma4(acc1, a1.y, w1); fma4(acc1, a1.z, w2); fma4(acc1, a1.w, w3);
        fma4(acc2, a2.x, w0); fma4(acc2, a2.y, w1); fma4(acc2, a2.z, w2); fma4(acc2, a2.w, w3);
        fma4(acc3, a3.x, w0); fma4(acc3, a3.y, w1); fma4(acc3, a3.z, w2); fma4(acc3, a3.w, w3);
    }

    __syncthreads();

    float4 bias = {0.f, 0.f, 0.f, 0.f};
    if (BIAS_RELU) bias = *(const float4*)(b + c0);

    float4 accs[4] = {acc0, acc1, acc2, acc3};
    #pragma unroll
    for (int r = 0; r < 4; ++r) {
        int row = row0 + r;
        if (row < n) {
            float4 v = accs[r];
            if (BIAS_RELU) {
                v.x = fmaxf(v.x + bias.x, 0.f);
                v.y = fmaxf(v.y + bias.y, 0.f);
                v.z = fmaxf(v.z + bias.z, 0.f);
                v.w = fmaxf(v.w + bias.w, 0.f);
            }
            *(float4*)(C + (size_t)row * FD + c0) = v;
        }
    }
}

// ---------- GCN gather: out[d] = relu( sum_{s in N(d)+self} dinv[s]dinv[d] m[s] + b ) ----------
// one wave (64 lanes) per node; lane owns 2 columns (float2)
__global__ __launch_bounds__(256) void k_gcn_gather(const float* __restrict__ m,
                                                    const int* __restrict__ col,
                                                    const int* __restrict__ rowptr,
                                                    const int* __restrict__ cnt,
                                                    const float* __restrict__ dinv,
                                                    const float* __restrict__ b,
                                                    float* __restrict__ out, int n) {
    const int wave = threadIdx.x >> 6;
    const int lane = threadIdx.x & 63;
    const int d = blockIdx.x * 4 + wave;
    if (d >= n) return;
    const int c0 = lane * 2;
    const float dd = dinv[d];

    float2 acc = *(const float2*)(m + (size_t)d * FD + c0);  // self term
    const float cs = dd * dd;
    acc.x *= cs; acc.y *= cs;

    const int beg = rowptr[d];
    const int deg = cnt[d];
    int j = 0;
    for (; j + 1 < deg; j += 2) {
        int s0 = col[beg + j];
        int s1 = col[beg + j + 1];
        float w0 = dd * dinv[s0];
        float w1 = dd * dinv[s1];
        float2 v0 = *(const float2*)(m + (size_t)s0 * FD + c0);
        float2 v1 = *(const float2*)(m + (size_t)s1 * FD + c0);
        acc.x = fmaf(w0, v0.x, acc.x); acc.y = fmaf(w0, v0.y, acc.y);
        acc.x = fmaf(w1, v1.x, acc.x); acc.y = fmaf(w1, v1.y, acc.y);
    }
    if (j < deg) {
        int s0 = col[beg + j];
        float w0 = dd * dinv[s0];
        float2 v0 = *(const float2*)(m + (size_t)s0 * FD + c0);
        acc.x = fmaf(w0, v0.x, acc.x); acc.y = fmaf(w0, v0.y, acc.y);
    }

    float2 bb = *(const float2*)(b + c0);
    acc.x = fmaxf(acc.x + bb.x, 0.f);
    acc.y = fmaxf(acc.y + bb.y, 0.f);
    *(float2*)(out + (size_t)d * FD + c0) = acc;
}

// ---------- GAT ----------
// per-node attention scalars: asrc[i] = g[i].a_src, adst[i] = g[i].a_dst
__global__ void k_av(const float* __restrict__ g, const float* __restrict__ a_src,
                     const float* __restrict__ a_dst, float* asrc, float* adst, int n) {
    int t = blockIdx.x * blockDim.x + threadIdx.x;
    int i = t >> 6, lane = t & 63;
    if (i >= n) return;
    float2 gv = *(const float2*)(g + (size_t)i * FD + lane * 2);
    float2 as = *(const float2*)(a_src + lane * 2);
    float2 ad = *(const float2*)(a_dst + lane * 2);
    float ps = gv.x * as.x + gv.y * as.y;
    float pd = gv.x * ad.x + gv.y * ad.y;
    #pragma unroll
    for (int m = 32; m; m >>= 1) {
        ps += __shfl_xor(ps, m);
        pd += __shfl_xor(pd, m);
    }
    if (lane == 0) { asrc[i] = ps; adst[i] = pd; }
}

// out val[d] = (sum_{s in N(d)+self} w_sd g[s]) / (sum w_sd),  w = exp(lrelu(asrc[s]+adst[d]))
// no max-subtraction: logits are O(+-10); exp is safe, math identical after the divide
__global__ __launch_bounds__(256) void k_gat_gather(const float* __restrict__ g,
                                                    const int* __restrict__ col,
                                                    const int* __restrict__ rowptr,
                                                    const int* __restrict__ cnt,
                                                    const float* __restrict__ asrc,
                                                    const float* __restrict__ adst,
                                                    float* __restrict__ val, int n) {
    const int wave = threadIdx.x >> 6;
    const int lane = threadIdx.x & 63;
    const int d = blockIdx.x * 4 + wave;
    if (d >= n) return;
    const int c0 = lane * 2;
    const float ad = adst[d];

    float es = expf(lrelu(asrc[d] + ad));  // self
    float denom = es;
    float2 gs = *(const float2*)(g + (size_t)d * FD + c0);
    float2 acc = make_float2(es * gs.x, es * gs.y);

    const int beg = rowptr[d];
    const int deg = cnt[d];
    int j = 0;
    for (; j + 1 < deg; j += 2) {
        int s0 = col[beg + j];
        int s1 = col[beg + j + 1];
        float w0 = expf(lrelu(asrc[s0] + ad));
        float w1 = expf(lrelu(asrc[s1] + ad));
        float2 v0 = *(const float2*)(g + (size_t)s0 * FD + c0);
        float2 v1 = *(const float2*)(g + (size_t)s1 * FD + c0);
        denom += w0 + w1;
        acc.x = fmaf(w0, v0.x, acc.x); acc.y = fmaf(w0, v0.y, acc.y);
        acc.x = fmaf(w1, v1.x, acc.x); acc.y = fmaf(w1, v1.y, acc.y);
    }
    if (j < deg) {
        int s0 = col[beg + j];
        float w0 = expf(lrelu(asrc[s0] + ad));
        float2 v0 = *(const float2*)(g + (size_t)s0 * FD + c0);
        denom += w0;
        acc.x = fmaf(w0, v0.x, acc.x); acc.y = fmaf(w0, v0.y, acc.y);
    }

    float inv = 1.0f / denom;
    *(float2*)(val + (size_t)d * FD + c0) = make_float2(acc.x * inv, acc.y * inv);
}

// ---------- final mean over nodes ----------
__global__ void k_zero_out(float* out) { out[threadIdx.x] = 0.f; }

__global__ void k_reduce_plain(const float* __restrict__ val, float* out, int n) {
    const int sub = threadIdx.x >> 7;  // 0..1
    const int c = threadIdx.x & 127;
    float r = 0.f;
    for (int i = blockIdx.x * 2 + sub; i < n; i += gridDim.x * 2)
        r += val[(size_t)i * FD + c];
    __shared__ float lds[256];
    lds[threadIdx.x] = r;
    __syncthreads();
    if (threadIdx.x < 128) atomicAdd(&out[c], lds[threadIdx.x] + lds[threadIdx.x + 128]);
}

__global__ void k_final(float* out, const float* __restrict__ bg, float invn) {
    int c = threadIdx.x;
    out[c] = out[c] * invn + bg[c];
}

// ---------- launch ----------
extern "C" void kernel_launch(void* const* d_in, const int* in_sizes, int n_in,
                              void* d_out, int out_size, void* d_ws, size_t ws_size,
                              hipStream_t stream) {
    const float* x      = (const float*)d_in[0];
    const int*   ei     = (const int*)d_in[1];
    const float* W_emb  = (const float*)d_in[2];
    const float* b_emb  = (const float*)d_in[3];
    const float* W1     = (const float*)d_in[4];
    const float* b1     = (const float*)d_in[5];
    const float* W2     = (const float*)d_in[6];
    const float* b2     = (const float*)d_in[7];
    const float* Wg     = (const float*)d_in[8];
    const float* a_src  = (const float*)d_in[9];
    const float* a_dst  = (const float*)d_in[10];
    const float* bg     = (const float*)d_in[11];

    const int n = in_sizes[0] / FD;   // 50000
    const int e = in_sizes[1] / 2;    // 800000
    const int* src = ei;
    const int* dst = ei + e;

    float* bufA  = (float*)d_ws;
    float* bufB  = bufA + (size_t)n * FD;
    float* dinv  = bufB + (size_t)n * FD;
    float* asrc  = dinv + n;
    float* adst  = asrc + n;
    int*   cnt    = (int*)(adst + n);
    int*   rowptr = cnt + n;
    int*   cursor = rowptr + n;
    int*   col    = cursor + n;
    int*   bsum   = col + e;

    const dim3 B(256);
    const int gn     = (n + 255) / 256;       // 196 blocks (<= 256, required by scan2)
    const int ge     = (e + 255) / 256;
    const int gnode4 = (n + 3) / 4;
    const int grows  = (n + 31) / 32;

    // ---- CSR build (counting sort by destination) ----
    k_zero_int<<<gn, B, 0, stream>>>(cnt, n);
    k_zero_int<<<gn, B, 0, stream>>>(cursor, n);
    k_hist<<<ge, B, 0, stream>>>(dst, cnt, e);
    k_scan1<<<gn, B, 0, stream>>>(cnt, rowptr, bsum, n);
    k_scan2<<<1, B, 0, stream>>>(bsum, gn);
    k_scan3<<<gn, B, 0, stream>>>(rowptr, cnt, bsum, n);
    k_fill<<<ge, B, 0, stream>>>(src, dst, rowptr, cursor, col, e);
    k_dinv<<<gn, B, 0, stream>>>(cnt, dinv, n);

    // ---- h0 = relu(x @ W_emb + b_emb) -> bufA ----
    k_gemm128<true><<<grows, B, 0, stream>>>(x, W_emb, b_emb, bufA, n);

    // ---- GCN layer 1 ----
    k_gemm128<false><<<grows, B, 0, stream>>>(bufA, W1, nullptr, bufA, n);
    k_gcn_gather<<<gnode4, B, 0, stream>>>(bufA, col, rowptr, cnt, dinv, b1, bufB, n);

    // ---- GCN layer 2 ----
    k_gemm128<false><<<grows, B, 0, stream>>>(bufB, W2, nullptr, bufB, n);
    k_gcn_gather<<<gnode4, B, 0, stream>>>(bufB, col, rowptr, cnt, dinv, b2, bufA, n);

    // ---- GAT ----
    k_gemm128<false><<<grows, B, 0, stream>>>(bufA, Wg, nullptr, bufA, n);
    k_av<<<(int)(((long long)n * 64 + 255) / 256), B, 0, stream>>>(bufA, a_src, a_dst, asrc, adst, n);
    k_gat_gather<<<gnode4, B, 0, stream>>>(bufA, col, rowptr, cnt, asrc, adst, bufB, n);

    // ---- out[c] = mean_i val[i][c] + bg[c] ----
    k_zero_out<<<1, FD, 0, stream>>>((float*)d_out);
    k_reduce_plain<<<256, B, 0, stream>>>(bufB, (float*)d_out, n);
    k_final<<<1, FD, 0, stream>>>((float*)d_out, bg, 1.0f / n);
}

// Round 5
// 475.209 us; speedup vs baseline: 9.3481x; 1.1712x over previous
//
#include <hip/hip_runtime.h>

#define FD 128  // feature dim (H = O = 128)

__device__ __forceinline__ float lrelu(float x) { return x > 0.f ? x : 0.2f * x; }

__device__ __forceinline__ void fma4(float4& acc, float s, const float4& w) {
    acc.x = fmaf(s, w.x, acc.x);
    acc.y = fmaf(s, w.y, acc.y);
    acc.z = fmaf(s, w.z, acc.z);
    acc.w = fmaf(s, w.w, acc.w);
}

// ---------- CSR build ----------
__global__ void k_zero_int(int* p, int n) {
    int i = blockIdx.x * blockDim.x + threadIdx.x;
    if (i < n) p[i] = 0;
}

__global__ void k_hist(const int* __restrict__ dst, int* cnt, int e) {
    int i = blockIdx.x * blockDim.x + threadIdx.x;
    if (i < e) atomicAdd(&cnt[dst[i]], 1);
}

// inclusive block scan -> rowptr (per-block inclusive), bsum = block totals
__global__ __launch_bounds__(256) void k_scan1(const int* __restrict__ cnt, int* rowptr,
                                               int* bsum, int n) {
    __shared__ int lds[256];
    int i = blockIdx.x * 256 + threadIdx.x;
    int v = (i < n) ? cnt[i] : 0;
    lds[threadIdx.x] = v;
    __syncthreads();
    for (int off = 1; off < 256; off <<= 1) {
        int t = (threadIdx.x >= off) ? lds[threadIdx.x - off] : 0;
        __syncthreads();
        lds[threadIdx.x] += t;
        __syncthreads();
    }
    if (i < n) rowptr[i] = lds[threadIdx.x];
    if (threadIdx.x == 255) bsum[blockIdx.x] = lds[255];
}

// single-block inclusive scan of block sums (nb <= 256)
__global__ __launch_bounds__(256) void k_scan2(int* bsum, int nb) {
    __shared__ int lds[256];
    int v = (threadIdx.x < nb) ? bsum[threadIdx.x] : 0;
    lds[threadIdx.x] = v;
    __syncthreads();
    for (int off = 1; off < 256; off <<= 1) {
        int t = (threadIdx.x >= off) ? lds[threadIdx.x - off] : 0;
        __syncthreads();
        lds[threadIdx.x] += t;
        __syncthreads();
    }
    if (threadIdx.x < nb) bsum[threadIdx.x] = lds[threadIdx.x];
}

// rowptr[i] = exclusive prefix = (inclusive within block) - cnt[i] + prev-block offset
__global__ void k_scan3(int* rowptr, const int* __restrict__ cnt,
                        const int* __restrict__ bsum, int n) {
    int i = blockIdx.x * 256 + threadIdx.x;
    if (i >= n) return;
    int off = (blockIdx.x > 0) ? bsum[blockIdx.x - 1] : 0;
    rowptr[i] = rowptr[i] - cnt[i] + off;
}

__global__ void k_fill(const int* __restrict__ src, const int* __restrict__ dst,
                       const int* __restrict__ rowptr, int* cursor, int* col, int e) {
    int i = blockIdx.x * blockDim.x + threadIdx.x;
    if (i >= e) return;
    int d = dst[i];
    int pos = atomicAdd(&cursor[d], 1);
    col[rowptr[d] + pos] = src[i];
}

__global__ void k_dinv(const int* __restrict__ cnt, float* dinv, int n) {
    int i = blockIdx.x * blockDim.x + threadIdx.x;
    if (i < n) dinv[i] = rsqrtf((float)cnt[i] + 1.0f);  // +1 self-loop
}

// ---------- GEMM: C[n,128] = act(A[n,128] @ W[128,128] (+ b)) ----------
// W staged in LDS (64 KB) once per block; block = 256 threads covers 64 rows;
// thread computes 8 rows x 4 cols (8 independent accumulators for ILP).
// A-row loads are wave-broadcast (lanes share addresses) -> L1-resident.
// In-place safe (A == C): all reads precede __syncthreads, stores after;
// rows are block-exclusive (clamped reads stay within the last block).
// AV epilogue (Wg layer): also writes asrc[row]=g.a_src, adst[row]=g.a_dst
// via intra-32-lane shuffle reduction (replaces the separate k_av kernel).
template <bool BIAS_RELU, bool AV>
__global__ __launch_bounds__(256) void k_gemm128(const float* A, const float* __restrict__ W,
                                                 const float* __restrict__ b, float* C,
                                                 const float* __restrict__ av_s,
                                                 const float* __restrict__ av_d,
                                                 float* asrc, float* adst, int n) {
    __shared__ float Ws[FD * FD];
    #pragma unroll
    for (int i = 0; i < 16; ++i) {
        int idx = (threadIdx.x + i * 256) * 4;
        *(float4*)&Ws[idx] = *(const float4*)&W[idx];
    }
    __syncthreads();

    const int tx = threadIdx.x & 31;   // col group: cols tx*4 .. tx*4+3
    const int ty = threadIdx.x >> 5;   // row subgroup 0..7
    const int c0 = tx * 4;
    const int row0 = blockIdx.x * 64 + ty * 8;

    const float* Ap[8];
    #pragma unroll
    for (int r = 0; r < 8; ++r) Ap[r] = A + (size_t)min(row0 + r, n - 1) * FD;

    float4 acc[8];
    #pragma unroll
    for (int r = 0; r < 8; ++r) acc[r] = make_float4(0.f, 0.f, 0.f, 0.f);

    for (int k = 0; k < FD; k += 4) {
        float4 w0 = *(const float4*)&Ws[(k + 0) * FD + c0];
        float4 w1 = *(const float4*)&Ws[(k + 1) * FD + c0];
        float4 w2 = *(const float4*)&Ws[(k + 2) * FD + c0];
        float4 w3 = *(const float4*)&Ws[(k + 3) * FD + c0];
        #pragma unroll
        for (int r = 0; r < 8; ++r) {
            float4 a = *(const float4*)(Ap[r] + k);
            fma4(acc[r], a.x, w0);
            fma4(acc[r], a.y, w1);
            fma4(acc[r], a.z, w2);
            fma4(acc[r], a.w, w3);
        }
    }

    __syncthreads();  // all in-place reads complete before any store

    float4 bias = {0.f, 0.f, 0.f, 0.f};
    if (BIAS_RELU) bias = *(const float4*)(b + c0);
    float4 as4 = {0.f, 0.f, 0.f, 0.f}, ad4 = as4;
    if (AV) {
        as4 = *(const float4*)(av_s + c0);
        ad4 = *(const float4*)(av_d + c0);
    }

    #pragma unroll
    for (int r = 0; r < 8; ++r) {
        int row = row0 + r;
        float4 v = acc[r];
        if (BIAS_RELU) {
            v.x = fmaxf(v.x + bias.x, 0.f);
            v.y = fmaxf(v.y + bias.y, 0.f);
            v.z = fmaxf(v.z + bias.z, 0.f);
            v.w = fmaxf(v.w + bias.w, 0.f);
        }
        if (row < n) *(float4*)(C + (size_t)row * FD + c0) = v;
        if (AV) {
            float ps = v.x * as4.x + v.y * as4.y + v.z * as4.z + v.w * as4.w;
            float pd = v.x * ad4.x + v.y * ad4.y + v.z * ad4.z + v.w * ad4.w;
            #pragma unroll
            for (int m = 16; m; m >>= 1) {
                ps += __shfl_xor(ps, m, 32);
                pd += __shfl_xor(pd, m, 32);
            }
            if (tx == 0 && row < n) { asrc[row] = ps; adst[row] = pd; }
        }
    }
}

// ---------- GCN gather: out[d] = relu( sum_{s in N(d)+self} dinv[s]dinv[d] m[s] + b ) ----------
// one wave (64 lanes) per node; lane owns 2 columns (float2)
__global__ __launch_bounds__(256) void k_gcn_gather(const float* __restrict__ m,
                                                    const int* __restrict__ col,
                                                    const int* __restrict__ rowptr,
                                                    const int* __restrict__ cnt,
                                                    const float* __restrict__ dinv,
                                                    const float* __restrict__ b,
                                                    float* __restrict__ out, int n) {
    const int wave = threadIdx.x >> 6;
    const int lane = threadIdx.x & 63;
    const int d = blockIdx.x * 4 + wave;
    if (d >= n) return;
    const int c0 = lane * 2;
    const float dd = dinv[d];

    float2 acc = *(const float2*)(m + (size_t)d * FD + c0);  // self term
    const float cs = dd * dd;
    acc.x *= cs; acc.y *= cs;

    const int beg = rowptr[d];
    const int deg = cnt[d];
    int j = 0;
    for (; j + 1 < deg; j += 2) {
        int s0 = col[beg + j];
        int s1 = col[beg + j + 1];
        float w0 = dd * dinv[s0];
        float w1 = dd * dinv[s1];
        float2 v0 = *(const float2*)(m + (size_t)s0 * FD + c0);
        float2 v1 = *(const float2*)(m + (size_t)s1 * FD + c0);
        acc.x = fmaf(w0, v0.x, acc.x); acc.y = fmaf(w0, v0.y, acc.y);
        acc.x = fmaf(w1, v1.x, acc.x); acc.y = fmaf(w1, v1.y, acc.y);
    }
    if (j < deg) {
        int s0 = col[beg + j];
        float w0 = dd * dinv[s0];
        float2 v0 = *(const float2*)(m + (size_t)s0 * FD + c0);
        acc.x = fmaf(w0, v0.x, acc.x); acc.y = fmaf(w0, v0.y, acc.y);
    }

    float2 bb = *(const float2*)(b + c0);
    acc.x = fmaxf(acc.x + bb.x, 0.f);
    acc.y = fmaxf(acc.y + bb.y, 0.f);
    *(float2*)(out + (size_t)d * FD + c0) = acc;
}

// ---------- GAT gather ----------
// val[d] = (sum_{s in N(d)+self} w_sd g[s]) / (sum w_sd),  w = exp(lrelu(asrc[s]+adst[d]))
// no max-subtraction: logits are O(+-10); exp is safe, math identical after the divide
__global__ __launch_bounds__(256) void k_gat_gather(const float* __restrict__ g,
                                                    const int* __restrict__ col,
                                                    const int* __restrict__ rowptr,
                                                    const int* __restrict__ cnt,
                                                    const float* __restrict__ asrc,
                                                    const float* __restrict__ adst,
                                                    float* __restrict__ val, int n) {
    const int wave = threadIdx.x >> 6;
    const int lane = threadIdx.x & 63;
    const int d = blockIdx.x * 4 + wave;
    if (d >= n) return;
    const int c0 = lane * 2;
    const float ad = adst[d];

    float es = expf(lrelu(asrc[d] + ad));  // self
    float denom = es;
    float2 gs = *(const float2*)(g + (size_t)d * FD + c0);
    float2 acc = make_float2(es * gs.x, es * gs.y);

    const int beg = rowptr[d];
    const int deg = cnt[d];
    int j = 0;
    for (; j + 1 < deg; j += 2) {
        int s0 = col[beg + j];
        int s1 = col[beg + j + 1];
        float w0 = expf(lrelu(asrc[s0] + ad));
        float w1 = expf(lrelu(asrc[s1] + ad));
        float2 v0 = *(const float2*)(g + (size_t)s0 * FD + c0);
        float2 v1 = *(const float2*)(g + (size_t)s1 * FD + c0);
        denom += w0 + w1;
        acc.x = fmaf(w0, v0.x, acc.x); acc.y = fmaf(w0, v0.y, acc.y);
        acc.x = fmaf(w1, v1.x, acc.x); acc.y = fmaf(w1, v1.y, acc.y);
    }
    if (j < deg) {
        int s0 = col[beg + j];
        float w0 = expf(lrelu(asrc[s0] + ad));
        float2 v0 = *(const float2*)(g + (size_t)s0 * FD + c0);
        denom += w0;
        acc.x = fmaf(w0, v0.x, acc.x); acc.y = fmaf(w0, v0.y, acc.y);
    }

    float inv = 1.0f / denom;
    *(float2*)(val + (size_t)d * FD + c0) = make_float2(acc.x * inv, acc.y * inv);
}

// ---------- final mean over nodes ----------
__global__ void k_zero_out(float* out) { out[threadIdx.x] = 0.f; }

__global__ void k_reduce_plain(const float* __restrict__ val, float* out, int n) {
    const int sub = threadIdx.x >> 7;  // 0..1
    const int c = threadIdx.x & 127;
    float r = 0.f;
    for (int i = blockIdx.x * 2 + sub; i < n; i += gridDim.x * 2)
        r += val[(size_t)i * FD + c];
    __shared__ float lds[256];
    lds[threadIdx.x] = r;
    __syncthreads();
    if (threadIdx.x < 128) atomicAdd(&out[c], lds[threadIdx.x] + lds[threadIdx.x + 128]);
}

__global__ void k_final(float* out, const float* __restrict__ bg, float invn) {
    int c = threadIdx.x;
    out[c] = out[c] * invn + bg[c];
}

// ---------- launch ----------
extern "C" void kernel_launch(void* const* d_in, const int* in_sizes, int n_in,
                              void* d_out, int out_size, void* d_ws, size_t ws_size,
                              hipStream_t stream) {
    const float* x      = (const float*)d_in[0];
    const int*   ei     = (const int*)d_in[1];
    const float* W_emb  = (const float*)d_in[2];
    const float* b_emb  = (const float*)d_in[3];
    const float* W1     = (const float*)d_in[4];
    const float* b1     = (const float*)d_in[5];
    const float* W2     = (const float*)d_in[6];
    const float* b2     = (const float*)d_in[7];
    const float* Wg     = (const float*)d_in[8];
    const float* a_src  = (const float*)d_in[9];
    const float* a_dst  = (const float*)d_in[10];
    const float* bg     = (const float*)d_in[11];

    const int n = in_sizes[0] / FD;   // 50000
    const int e = in_sizes[1] / 2;    // 800000
    const int* src = ei;
    const int* dst = ei + e;

    float* bufA  = (float*)d_ws;
    float* bufB  = bufA + (size_t)n * FD;
    float* dinv  = bufB + (size_t)n * FD;
    float* asrc  = dinv + n;
    float* adst  = asrc + n;
    int*   cnt    = (int*)(adst + n);
    int*   rowptr = cnt + n;
    int*   cursor = rowptr + n;
    int*   col    = cursor + n;
    int*   bsum   = col + e;

    const dim3 B(256);
    const int gn     = (n + 255) / 256;   // 196 blocks (<= 256, required by scan2)
    const int ge     = (e + 255) / 256;
    const int gnode4 = (n + 3) / 4;
    const int gb64   = (n + 63) / 64;

    // ---- CSR build (counting sort by destination) ----
    k_zero_int<<<gn, B, 0, stream>>>(cnt, n);
    k_zero_int<<<gn, B, 0, stream>>>(cursor, n);
    k_hist<<<ge, B, 0, stream>>>(dst, cnt, e);
    k_scan1<<<gn, B, 0, stream>>>(cnt, rowptr, bsum, n);
    k_scan2<<<1, B, 0, stream>>>(bsum, gn);
    k_scan3<<<gn, B, 0, stream>>>(rowptr, cnt, bsum, n);
    k_fill<<<ge, B, 0, stream>>>(src, dst, rowptr, cursor, col, e);
    k_dinv<<<gn, B, 0, stream>>>(cnt, dinv, n);

    // ---- h0 = relu(x @ W_emb + b_emb) -> bufA ----
    k_gemm128<true, false><<<gb64, B, 0, stream>>>(x, W_emb, b_emb, bufA,
                                                   nullptr, nullptr, nullptr, nullptr, n);

    // ---- GCN layer 1 ----
    k_gemm128<false, false><<<gb64, B, 0, stream>>>(bufA, W1, nullptr, bufA,
                                                    nullptr, nullptr, nullptr, nullptr, n);
    k_gcn_gather<<<gnode4, B, 0, stream>>>(bufA, col, rowptr, cnt, dinv, b1, bufB, n);

    // ---- GCN layer 2 ----
    k_gemm128<false, false><<<gb64, B, 0, stream>>>(bufB, W2, nullptr, bufB,
                                                    nullptr, nullptr, nullptr, nullptr, n);
    k_gcn_gather<<<gnode4, B, 0, stream>>>(bufB, col, rowptr, cnt, dinv, b2, bufA, n);

    // ---- GAT: g = h2 @ Wg (in-place), fused a_src/a_dst projections ----
    k_gemm128<false, true><<<gb64, B, 0, stream>>>(bufA, Wg, nullptr, bufA,
                                                   a_src, a_dst, asrc, adst, n);
    k_gat_gather<<<gnode4, B, 0, stream>>>(bufA, col, rowptr, cnt, asrc, adst, bufB, n);

    // ---- out[c] = mean_i val[i][c] + bg[c] ----
    k_zero_out<<<1, FD, 0, stream>>>((float*)d_out);
    k_reduce_plain<<<256, B, 0, stream>>>(bufB, (float*)d_out, n);
    k_final<<<1, FD, 0, stream>>>((float*)d_out, bg, 1.0f / n);
}